// Round 1
// baseline (2268.779 us; speedup 1.0000x reference)
//
#include <hip/hip_runtime.h>

#define NNODES 100000
#define NEDGES 1600000
#define FIN 128
#define DIM 32
#define BN_EPS 1e-5f

// ---------------------------------------------------------------------------
// K1: z = x @ w1a   (N x 128) @ (128 x 32) -> (N x 32)
// Half-wave (32 lanes) per node. w1a staged in LDS (16 KB).
// ---------------------------------------------------------------------------
__global__ void k_proj1(const float* __restrict__ x,
                        const float* __restrict__ w,
                        float* __restrict__ z) {
    __shared__ float sw[FIN * DIM];
    for (int i = threadIdx.x; i < FIN * DIM; i += blockDim.x) sw[i] = w[i];
    __syncthreads();

    const int lane = threadIdx.x & 31;
    const int hw   = (blockIdx.x * blockDim.x + threadIdx.x) >> 5;
    const int nhw  = (gridDim.x * blockDim.x) >> 5;

    for (int i = hw; i < NNODES; i += nhw) {
        float xv[4];
#pragma unroll
        for (int c = 0; c < 4; ++c) xv[c] = x[i * FIN + c * 32 + lane];
        float acc = 0.f;
#pragma unroll
        for (int c = 0; c < 4; ++c) {
#pragma unroll
            for (int j = 0; j < 32; ++j) {
                float xj = __shfl(xv[c], j, 32);
                acc += xj * sw[(c * 32 + j) * DIM + lane];
            }
        }
        z[i * DIM + lane] = acc;
    }
}

// ---------------------------------------------------------------------------
// K2: agg[dst] += z[src] over all edges. 8 lanes per edge, float4 gather,
// 4 scalar f32 atomics per lane (coalesced within the 32-float row).
// ---------------------------------------------------------------------------
__global__ void k_scatter(const int* __restrict__ ei,
                          const float* __restrict__ z,
                          float* __restrict__ agg) {
    const int tid    = blockIdx.x * blockDim.x + threadIdx.x;
    const int stride = gridDim.x * blockDim.x;
    const int total  = NEDGES * 8;
    for (int idx = tid; idx < total; idx += stride) {
        const int e = idx >> 3;
        const int q = idx & 7;
        const int s = ei[e];
        const int d = ei[NEDGES + e];
        const float4 zv = *reinterpret_cast<const float4*>(&z[s * DIM + q * 4]);
        float* ap = &agg[d * DIM + q * 4];
        atomicAdd(ap + 0, zv.x);
        atomicAdd(ap + 1, zv.y);
        atomicAdd(ap + 2, zv.z);
        atomicAdd(ap + 3, zv.w);
    }
}

// ---------------------------------------------------------------------------
// K3: per node: t = relu(z + agg + ba); h = relu(t @ wb + bb).
// Also accumulate per-feature sum / sumsq for BN (block-reduce + atomics).
// ---------------------------------------------------------------------------
__global__ void k_mlp(const float* __restrict__ z,
                      const float* __restrict__ agg,
                      const float* __restrict__ ba,
                      const float* __restrict__ wb,
                      const float* __restrict__ bb,
                      float* __restrict__ h,
                      float* __restrict__ stats) {  // stats[0..31]=sum, [32..63]=sumsq
    __shared__ float sw[DIM * DIM];
    __shared__ float ssum[DIM], ssq[DIM];
    for (int i = threadIdx.x; i < DIM * DIM; i += blockDim.x) sw[i] = wb[i];
    if (threadIdx.x < DIM) { ssum[threadIdx.x] = 0.f; ssq[threadIdx.x] = 0.f; }
    __syncthreads();

    const int lane = threadIdx.x & 31;
    const float bak = ba[lane];
    const float bbk = bb[lane];
    const int hw  = (blockIdx.x * blockDim.x + threadIdx.x) >> 5;
    const int nhw = (gridDim.x * blockDim.x) >> 5;

    float lsum = 0.f, lsq = 0.f;
    for (int i = hw; i < NNODES; i += nhw) {
        float t = z[i * DIM + lane] + agg[i * DIM + lane] + bak;
        t = fmaxf(t, 0.f);
        float acc = bbk;
#pragma unroll
        for (int j = 0; j < 32; ++j) {
            float tj = __shfl(t, j, 32);
            acc += tj * sw[j * DIM + lane];
        }
        acc = fmaxf(acc, 0.f);
        h[i * DIM + lane] = acc;
        lsum += acc;
        lsq  += acc * acc;
    }
    atomicAdd(&ssum[lane], lsum);
    atomicAdd(&ssq[lane], lsq);
    __syncthreads();
    if (threadIdx.x < DIM) {
        atomicAdd(&stats[threadIdx.x],        ssum[threadIdx.x]);
        atomicAdd(&stats[DIM + threadIdx.x],  ssq[threadIdx.x]);
    }
}

// ---------------------------------------------------------------------------
// K4: z = BN(h) @ wa, with BN folded into the weights:
//   BN(h)_j = h_j * s_j + t_j
//   z_k = sum_j h_j * (s_j * wa[j][k]) + sum_j t_j * wa[j][k]
// ---------------------------------------------------------------------------
__global__ void k_projbn(const float* __restrict__ h,
                         const float* __restrict__ stats,
                         const float* __restrict__ g,
                         const float* __restrict__ be,
                         const float* __restrict__ wa,
                         float* __restrict__ z) {
    __shared__ float sw[DIM * DIM];
    __shared__ float sconst[DIM];
    __shared__ float ss[DIM], st[DIM];
    if (threadIdx.x < DIM) {
        float mu  = stats[threadIdx.x] * (1.f / NNODES);
        float var = stats[DIM + threadIdx.x] * (1.f / NNODES) - mu * mu;
        float sc  = g[threadIdx.x] * rsqrtf(var + BN_EPS);
        ss[threadIdx.x] = sc;
        st[threadIdx.x] = be[threadIdx.x] - mu * sc;
    }
    __syncthreads();
    for (int i = threadIdx.x; i < DIM * DIM; i += blockDim.x) {
        int j = i >> 5;
        sw[i] = ss[j] * wa[i];
    }
    __syncthreads();
    if (threadIdx.x < DIM) {
        float c = 0.f;
        for (int j = 0; j < DIM; ++j) c += st[j] * wa[j * DIM + threadIdx.x];
        sconst[threadIdx.x] = c;
    }
    __syncthreads();

    const int lane = threadIdx.x & 31;
    const int hw  = (blockIdx.x * blockDim.x + threadIdx.x) >> 5;
    const int nhw = (gridDim.x * blockDim.x) >> 5;
    for (int i = hw; i < NNODES; i += nhw) {
        float hv = h[i * DIM + lane];
        float acc = sconst[lane];
#pragma unroll
        for (int j = 0; j < 32; ++j) {
            float hj = __shfl(hv, j, 32);
            acc += hj * sw[j * DIM + lane];
        }
        z[i * DIM + lane] = acc;
    }
}

// ---------------------------------------------------------------------------
// K5: head: out = relu(BN(h3) @ fw1 + fb1) @ fw2 + fb2   (N x 2)
// BN folded into fw1 as in K4.
// ---------------------------------------------------------------------------
__global__ void k_head(const float* __restrict__ h,
                       const float* __restrict__ stats,
                       const float* __restrict__ g,
                       const float* __restrict__ be,
                       const float* __restrict__ fw1,
                       const float* __restrict__ fb1,
                       const float* __restrict__ fw2,
                       const float* __restrict__ fb2,
                       float* __restrict__ out) {
    __shared__ float sw[DIM * DIM];
    __shared__ float sconst[DIM];
    __shared__ float ss[DIM], st[DIM];
    __shared__ float sw2[DIM * 2];
    if (threadIdx.x < DIM) {
        float mu  = stats[threadIdx.x] * (1.f / NNODES);
        float var = stats[DIM + threadIdx.x] * (1.f / NNODES) - mu * mu;
        float sc  = g[threadIdx.x] * rsqrtf(var + BN_EPS);
        ss[threadIdx.x] = sc;
        st[threadIdx.x] = be[threadIdx.x] - mu * sc;
    }
    __syncthreads();
    for (int i = threadIdx.x; i < DIM * DIM; i += blockDim.x) {
        int j = i >> 5;
        sw[i] = ss[j] * fw1[i];
    }
    if (threadIdx.x < DIM * 2) sw2[threadIdx.x] = fw2[threadIdx.x];
    __syncthreads();
    if (threadIdx.x < DIM) {
        float c = fb1[threadIdx.x];
        for (int j = 0; j < DIM; ++j) c += st[j] * fw1[j * DIM + threadIdx.x];
        sconst[threadIdx.x] = c;
    }
    __syncthreads();

    const float fb2_0 = fb2[0];
    const float fb2_1 = fb2[1];
    const int lane = threadIdx.x & 31;
    const int hw  = (blockIdx.x * blockDim.x + threadIdx.x) >> 5;
    const int nhw = (gridDim.x * blockDim.x) >> 5;
    for (int i = hw; i < NNODES; i += nhw) {
        float hv = h[i * DIM + lane];
        float acc = sconst[lane];
#pragma unroll
        for (int j = 0; j < 32; ++j) {
            float hj = __shfl(hv, j, 32);
            acc += hj * sw[j * DIM + lane];
        }
        float u = fmaxf(acc, 0.f);
        float p0 = u * sw2[lane * 2 + 0];
        float p1 = u * sw2[lane * 2 + 1];
#pragma unroll
        for (int off = 16; off >= 1; off >>= 1) {
            p0 += __shfl_xor(p0, off, 32);
            p1 += __shfl_xor(p1, off, 32);
        }
        if (lane == 0) {
            out[i * 2 + 0] = p0 + fb2_0;
            out[i * 2 + 1] = p1 + fb2_1;
        }
    }
}

extern "C" void kernel_launch(void* const* d_in, const int* in_sizes, int n_in,
                              void* d_out, int out_size, void* d_ws, size_t ws_size,
                              hipStream_t stream) {
    const float* x   = (const float*)d_in[0];
    const int*   ei  = (const int*)d_in[1];
    // d_in[2] edge_attr, d_in[3] batch: unused by the reference computation
    const float* w1a = (const float*)d_in[4];
    const float* b1a = (const float*)d_in[5];
    const float* w1b = (const float*)d_in[6];
    const float* b1b = (const float*)d_in[7];
    const float* g1  = (const float*)d_in[8];
    const float* be1 = (const float*)d_in[9];
    const float* w2a = (const float*)d_in[10];
    const float* b2a = (const float*)d_in[11];
    const float* w2b = (const float*)d_in[12];
    const float* b2b = (const float*)d_in[13];
    const float* g2  = (const float*)d_in[14];
    const float* be2 = (const float*)d_in[15];
    const float* w3a = (const float*)d_in[16];
    const float* b3a = (const float*)d_in[17];
    const float* w3b = (const float*)d_in[18];
    const float* b3b = (const float*)d_in[19];
    const float* g3  = (const float*)d_in[20];
    const float* be3 = (const float*)d_in[21];
    const float* fw1 = (const float*)d_in[22];
    const float* fb1 = (const float*)d_in[23];
    const float* fw2 = (const float*)d_in[24];
    const float* fb2 = (const float*)d_in[25];
    float* out = (float*)d_out;

    float* ws    = (float*)d_ws;
    const size_t nf = (size_t)NNODES * DIM;
    float* z     = ws;
    float* agg   = ws + nf;
    float* h     = ws + 2 * nf;
    float* stats = ws + 3 * nf;  // 3 layers x 64 floats

    const int NB_NODE = 1024, NB_EDGE = 2048, TB = 256;

    hipMemsetAsync(stats, 0, 3 * 64 * sizeof(float), stream);

    // ---- layer 1 ----
    k_proj1<<<NB_NODE, TB, 0, stream>>>(x, w1a, z);
    hipMemsetAsync(agg, 0, nf * sizeof(float), stream);
    k_scatter<<<NB_EDGE, TB, 0, stream>>>(ei, z, agg);
    k_mlp<<<NB_NODE, TB, 0, stream>>>(z, agg, b1a, w1b, b1b, h, stats + 0);

    // ---- layer 2 ----
    k_projbn<<<NB_NODE, TB, 0, stream>>>(h, stats + 0, g1, be1, w2a, z);
    hipMemsetAsync(agg, 0, nf * sizeof(float), stream);
    k_scatter<<<NB_EDGE, TB, 0, stream>>>(ei, z, agg);
    k_mlp<<<NB_NODE, TB, 0, stream>>>(z, agg, b2a, w2b, b2b, h, stats + 64);

    // ---- layer 3 ----
    k_projbn<<<NB_NODE, TB, 0, stream>>>(h, stats + 64, g2, be2, w3a, z);
    hipMemsetAsync(agg, 0, nf * sizeof(float), stream);
    k_scatter<<<NB_EDGE, TB, 0, stream>>>(ei, z, agg);
    k_mlp<<<NB_NODE, TB, 0, stream>>>(z, agg, b3a, w3b, b3b, h, stats + 128);

    // ---- head ----
    k_head<<<NB_NODE, TB, 0, stream>>>(h, stats + 128, g3, be3,
                                       fw1, fb1, fw2, fb2, out);
}

// Round 2
// 877.553 us; speedup vs baseline: 2.5853x; 2.5853x over previous
//
#include <hip/hip_runtime.h>

#define NNODES 100000
#define NEDGES 1600000
#define FIN 128
#define DIM 32
#define BN_EPS 1e-5f
#define SCAN_THREADS 1024

// ---------------------------------------------------------------------------
// K1: z = x @ w1a   (N x 128) @ (128 x 32) -> (N x 32)
// Half-wave (32 lanes) per node. w1a staged in LDS (16 KB).
// ---------------------------------------------------------------------------
__global__ void k_proj1(const float* __restrict__ x,
                        const float* __restrict__ w,
                        float* __restrict__ z) {
    __shared__ float sw[FIN * DIM];
    for (int i = threadIdx.x; i < FIN * DIM; i += blockDim.x) sw[i] = w[i];
    __syncthreads();

    const int lane = threadIdx.x & 31;
    const int hw   = (blockIdx.x * blockDim.x + threadIdx.x) >> 5;
    const int nhw  = (gridDim.x * blockDim.x) >> 5;

    for (int i = hw; i < NNODES; i += nhw) {
        float xv[4];
#pragma unroll
        for (int c = 0; c < 4; ++c) xv[c] = x[i * FIN + c * 32 + lane];
        float acc = 0.f;
#pragma unroll
        for (int c = 0; c < 4; ++c) {
#pragma unroll
            for (int j = 0; j < 32; ++j) {
                float xj = __shfl(xv[c], j, 32);
                acc += xj * sw[(c * 32 + j) * DIM + lane];
            }
        }
        z[i * DIM + lane] = acc;
    }
}

// ---------------------------------------------------------------------------
// CSR build (graph is identical for all 3 layers; build once per call).
// ---------------------------------------------------------------------------
__global__ void k_hist(const int* __restrict__ ei, int* __restrict__ deg) {
    const int tid    = blockIdx.x * blockDim.x + threadIdx.x;
    const int stride = gridDim.x * blockDim.x;
    for (int e = tid; e < NEDGES; e += stride)
        atomicAdd(&deg[ei[NEDGES + e]], 1);
}

// single-block exclusive scan of deg -> rowstart
__global__ void k_scan(const int* __restrict__ deg, int* __restrict__ rowstart) {
    __shared__ int ssum[SCAN_THREADS];
    const int chunk = (NNODES + SCAN_THREADS - 1) / SCAN_THREADS;
    const int t  = threadIdx.x;
    const int lo = t * chunk;
    const int hi = min(lo + chunk, NNODES);
    int s = 0;
    for (int i = lo; i < hi; ++i) s += deg[i];
    ssum[t] = s;
    __syncthreads();
    for (int off = 1; off < SCAN_THREADS; off <<= 1) {
        int v = (t >= off) ? ssum[t - off] : 0;
        __syncthreads();
        ssum[t] += v;
        __syncthreads();
    }
    int run = (t == 0) ? 0 : ssum[t - 1];
    for (int i = lo; i < hi; ++i) { rowstart[i] = run; run += deg[i]; }
}

__global__ void k_fill(const int* __restrict__ ei,
                       const int* __restrict__ rowstart,
                       int* __restrict__ cursor,
                       int* __restrict__ sorted_src) {
    const int tid    = blockIdx.x * blockDim.x + threadIdx.x;
    const int stride = gridDim.x * blockDim.x;
    for (int e = tid; e < NEDGES; e += stride) {
        const int s = ei[e];
        const int d = ei[NEDGES + e];
        const int pos = atomicAdd(&cursor[d], 1);
        sorted_src[rowstart[d] + pos] = s;
    }
}

// ---------------------------------------------------------------------------
// K3: fused gather + MLP + BN-stats. Per node (half-wave, lane=feature):
//   agg  = sum_{j in CSR row} z[j]          (gather, no float atomics)
//   t    = relu(z_i + agg + ba)
//   h_i  = relu(t @ wb + bb), accumulate sum/sumsq for BN
// ---------------------------------------------------------------------------
__global__ void k_gather_mlp(const float* __restrict__ z,
                             const int* __restrict__ rowstart,
                             const int* __restrict__ deg,
                             const int* __restrict__ sorted_src,
                             const float* __restrict__ ba,
                             const float* __restrict__ wb,
                             const float* __restrict__ bb,
                             float* __restrict__ h,
                             float* __restrict__ stats) {
    __shared__ float sw[DIM * DIM];
    __shared__ float ssum[DIM], ssq[DIM];
    for (int i = threadIdx.x; i < DIM * DIM; i += blockDim.x) sw[i] = wb[i];
    if (threadIdx.x < DIM) { ssum[threadIdx.x] = 0.f; ssq[threadIdx.x] = 0.f; }
    __syncthreads();

    const int lane = threadIdx.x & 31;
    const float bak = ba[lane];
    const float bbk = bb[lane];
    const int hw  = (blockIdx.x * blockDim.x + threadIdx.x) >> 5;
    const int nhw = (gridDim.x * blockDim.x) >> 5;

    float lsum = 0.f, lsq = 0.f;
    for (int i = hw; i < NNODES; i += nhw) {
        const int base = rowstart[i];
        const int cnt  = deg[i];
        float agg = 0.f;
        for (int k0 = 0; k0 < cnt; k0 += 32) {
            int e = 0;
            if (k0 + lane < cnt) e = sorted_src[base + k0 + lane];
            const int m = min(32, cnt - k0);
            for (int j = 0; j < m; ++j) {
                const int src = __shfl(e, j, 32);
                agg += z[src * DIM + lane];
            }
        }
        float t = z[i * DIM + lane] + agg + bak;
        t = fmaxf(t, 0.f);
        float acc = bbk;
#pragma unroll
        for (int j = 0; j < 32; ++j) {
            const float tj = __shfl(t, j, 32);
            acc += tj * sw[j * DIM + lane];
        }
        acc = fmaxf(acc, 0.f);
        h[i * DIM + lane] = acc;
        lsum += acc;
        lsq  += acc * acc;
    }
    atomicAdd(&ssum[lane], lsum);
    atomicAdd(&ssq[lane], lsq);
    __syncthreads();
    if (threadIdx.x < DIM) {
        atomicAdd(&stats[threadIdx.x],       ssum[threadIdx.x]);
        atomicAdd(&stats[DIM + threadIdx.x], ssq[threadIdx.x]);
    }
}

// ---------------------------------------------------------------------------
// K4: z = BN(h) @ wa, BN folded into the weights.
// ---------------------------------------------------------------------------
__global__ void k_projbn(const float* __restrict__ h,
                         const float* __restrict__ stats,
                         const float* __restrict__ g,
                         const float* __restrict__ be,
                         const float* __restrict__ wa,
                         float* __restrict__ z) {
    __shared__ float sw[DIM * DIM];
    __shared__ float sconst[DIM];
    __shared__ float ss[DIM], st[DIM];
    if (threadIdx.x < DIM) {
        float mu  = stats[threadIdx.x] * (1.f / NNODES);
        float var = stats[DIM + threadIdx.x] * (1.f / NNODES) - mu * mu;
        float sc  = g[threadIdx.x] * rsqrtf(var + BN_EPS);
        ss[threadIdx.x] = sc;
        st[threadIdx.x] = be[threadIdx.x] - mu * sc;
    }
    __syncthreads();
    for (int i = threadIdx.x; i < DIM * DIM; i += blockDim.x) {
        int j = i >> 5;
        sw[i] = ss[j] * wa[i];
    }
    __syncthreads();
    if (threadIdx.x < DIM) {
        float c = 0.f;
        for (int j = 0; j < DIM; ++j) c += st[j] * wa[j * DIM + threadIdx.x];
        sconst[threadIdx.x] = c;
    }
    __syncthreads();

    const int lane = threadIdx.x & 31;
    const int hw  = (blockIdx.x * blockDim.x + threadIdx.x) >> 5;
    const int nhw = (gridDim.x * blockDim.x) >> 5;
    for (int i = hw; i < NNODES; i += nhw) {
        float hv = h[i * DIM + lane];
        float acc = sconst[lane];
#pragma unroll
        for (int j = 0; j < 32; ++j) {
            const float hj = __shfl(hv, j, 32);
            acc += hj * sw[j * DIM + lane];
        }
        z[i * DIM + lane] = acc;
    }
}

// ---------------------------------------------------------------------------
// K5: head: out = relu(BN(h3) @ fw1 + fb1) @ fw2 + fb2   (N x 2)
// ---------------------------------------------------------------------------
__global__ void k_head(const float* __restrict__ h,
                       const float* __restrict__ stats,
                       const float* __restrict__ g,
                       const float* __restrict__ be,
                       const float* __restrict__ fw1,
                       const float* __restrict__ fb1,
                       const float* __restrict__ fw2,
                       const float* __restrict__ fb2,
                       float* __restrict__ out) {
    __shared__ float sw[DIM * DIM];
    __shared__ float sconst[DIM];
    __shared__ float ss[DIM], st[DIM];
    __shared__ float sw2[DIM * 2];
    if (threadIdx.x < DIM) {
        float mu  = stats[threadIdx.x] * (1.f / NNODES);
        float var = stats[DIM + threadIdx.x] * (1.f / NNODES) - mu * mu;
        float sc  = g[threadIdx.x] * rsqrtf(var + BN_EPS);
        ss[threadIdx.x] = sc;
        st[threadIdx.x] = be[threadIdx.x] - mu * sc;
    }
    __syncthreads();
    for (int i = threadIdx.x; i < DIM * DIM; i += blockDim.x) {
        int j = i >> 5;
        sw[i] = ss[j] * fw1[i];
    }
    if (threadIdx.x < DIM * 2) sw2[threadIdx.x] = fw2[threadIdx.x];
    __syncthreads();
    if (threadIdx.x < DIM) {
        float c = fb1[threadIdx.x];
        for (int j = 0; j < DIM; ++j) c += st[j] * fw1[j * DIM + threadIdx.x];
        sconst[threadIdx.x] = c;
    }
    __syncthreads();

    const float fb2_0 = fb2[0];
    const float fb2_1 = fb2[1];
    const int lane = threadIdx.x & 31;
    const int hw  = (blockIdx.x * blockDim.x + threadIdx.x) >> 5;
    const int nhw = (gridDim.x * blockDim.x) >> 5;
    for (int i = hw; i < NNODES; i += nhw) {
        float hv = h[i * DIM + lane];
        float acc = sconst[lane];
#pragma unroll
        for (int j = 0; j < 32; ++j) {
            const float hj = __shfl(hv, j, 32);
            acc += hj * sw[j * DIM + lane];
        }
        float u = fmaxf(acc, 0.f);
        float p0 = u * sw2[lane * 2 + 0];
        float p1 = u * sw2[lane * 2 + 1];
#pragma unroll
        for (int off = 16; off >= 1; off >>= 1) {
            p0 += __shfl_xor(p0, off, 32);
            p1 += __shfl_xor(p1, off, 32);
        }
        if (lane == 0) {
            out[i * 2 + 0] = p0 + fb2_0;
            out[i * 2 + 1] = p1 + fb2_1;
        }
    }
}

extern "C" void kernel_launch(void* const* d_in, const int* in_sizes, int n_in,
                              void* d_out, int out_size, void* d_ws, size_t ws_size,
                              hipStream_t stream) {
    const float* x   = (const float*)d_in[0];
    const int*   ei  = (const int*)d_in[1];
    const float* w1a = (const float*)d_in[4];
    const float* b1a = (const float*)d_in[5];
    const float* w1b = (const float*)d_in[6];
    const float* b1b = (const float*)d_in[7];
    const float* g1  = (const float*)d_in[8];
    const float* be1 = (const float*)d_in[9];
    const float* w2a = (const float*)d_in[10];
    const float* b2a = (const float*)d_in[11];
    const float* w2b = (const float*)d_in[12];
    const float* b2b = (const float*)d_in[13];
    const float* g2  = (const float*)d_in[14];
    const float* be2 = (const float*)d_in[15];
    const float* w3a = (const float*)d_in[16];
    const float* b3a = (const float*)d_in[17];
    const float* w3b = (const float*)d_in[18];
    const float* b3b = (const float*)d_in[19];
    const float* g3  = (const float*)d_in[20];
    const float* be3 = (const float*)d_in[21];
    const float* fw1 = (const float*)d_in[22];
    const float* fb1 = (const float*)d_in[23];
    const float* fw2 = (const float*)d_in[24];
    const float* fb2 = (const float*)d_in[25];
    float* out = (float*)d_out;

    float* ws = (float*)d_ws;
    const size_t nf = (size_t)NNODES * DIM;
    float* z     = ws;
    float* h     = ws + nf;
    float* stats = ws + 2 * nf;           // 3 layers x 64 floats
    int* deg        = (int*)(ws + 2 * nf + 192);
    int* rowstart   = deg + NNODES;
    int* cursor     = rowstart + NNODES;
    int* sorted_src = cursor + NNODES;    // NEDGES ints

    const int NB_NODE = 1024, NB_EDGE = 2048, TB = 256;

    hipMemsetAsync(stats, 0, 3 * 64 * sizeof(float), stream);
    hipMemsetAsync(deg, 0, NNODES * sizeof(int), stream);
    hipMemsetAsync(cursor, 0, NNODES * sizeof(int), stream);

    // CSR build (once; reused by all 3 layers)
    k_hist<<<NB_EDGE, TB, 0, stream>>>(ei, deg);
    k_scan<<<1, SCAN_THREADS, 0, stream>>>(deg, rowstart);
    k_fill<<<NB_EDGE, TB, 0, stream>>>(ei, rowstart, cursor, sorted_src);

    // ---- layer 1 ----
    k_proj1<<<NB_NODE, TB, 0, stream>>>(x, w1a, z);
    k_gather_mlp<<<NB_NODE, TB, 0, stream>>>(z, rowstart, deg, sorted_src,
                                             b1a, w1b, b1b, h, stats + 0);
    // ---- layer 2 ----
    k_projbn<<<NB_NODE, TB, 0, stream>>>(h, stats + 0, g1, be1, w2a, z);
    k_gather_mlp<<<NB_NODE, TB, 0, stream>>>(z, rowstart, deg, sorted_src,
                                             b2a, w2b, b2b, h, stats + 64);
    // ---- layer 3 ----
    k_projbn<<<NB_NODE, TB, 0, stream>>>(h, stats + 64, g2, be2, w3a, z);
    k_gather_mlp<<<NB_NODE, TB, 0, stream>>>(z, rowstart, deg, sorted_src,
                                             b3a, w3b, b3b, h, stats + 128);
    // ---- head ----
    k_head<<<NB_NODE, TB, 0, stream>>>(h, stats + 128, g3, be3,
                                       fw1, fb1, fw2, fb2, out);
}

// Round 3
// 615.911 us; speedup vs baseline: 3.6836x; 1.4248x over previous
//
#include <hip/hip_runtime.h>

#define NNODES 100000
#define NEDGES 1600000
#define FIN 128
#define DIM 32
#define BN_EPS 1e-5f
#define SC_T 1024
#define SC_B ((NNODES + SC_T - 1) / SC_T)   // 98 blocks

// ---------------------------------------------------------------------------
// K1: z = x @ w1a   (N x 128) @ (128 x 32) -> (N x 32)
// Half-wave per node; lane loads float4 (16B) of the x-row; w1a in LDS.
// ---------------------------------------------------------------------------
__global__ void k_proj1(const float* __restrict__ x,
                        const float* __restrict__ w,
                        float* __restrict__ z) {
    __shared__ float sw[FIN * DIM];
    for (int i = threadIdx.x; i < FIN * DIM; i += blockDim.x) sw[i] = w[i];
    __syncthreads();

    const int lane = threadIdx.x & 31;
    const int hw   = (blockIdx.x * blockDim.x + threadIdx.x) >> 5;
    const int nhw  = (gridDim.x * blockDim.x) >> 5;

    for (int i = hw; i < NNODES; i += nhw) {
        const float4 xv = reinterpret_cast<const float4*>(&x[(size_t)i * FIN])[lane];
        float xa[4] = {xv.x, xv.y, xv.z, xv.w};
        float acc = 0.f;
#pragma unroll
        for (int j = 0; j < FIN; ++j) {
            const float xj = __shfl(xa[j & 3], j >> 2, 32);
            acc += xj * sw[j * DIM + lane];
        }
        z[i * DIM + lane] = acc;
    }
}

// ---------------------------------------------------------------------------
// CSR build (graph identical for all 3 layers; built once per call).
// ---------------------------------------------------------------------------
__global__ void k_hist(const int* __restrict__ ei, int* __restrict__ deg) {
    const int tid    = blockIdx.x * blockDim.x + threadIdx.x;
    const int stride = gridDim.x * blockDim.x;
    for (int e = tid; e < NEDGES; e += stride)
        atomicAdd(&deg[ei[NEDGES + e]], 1);
}

// hierarchical scan: block-local inclusive scan + partials
__global__ void k_scan1(const int* __restrict__ deg,
                        int* __restrict__ rowstart,
                        int* __restrict__ partials) {
    __shared__ int sbuf[SC_T];
    const int t = threadIdx.x;
    const int i = blockIdx.x * SC_T + t;
    const int v = (i < NNODES) ? deg[i] : 0;
    sbuf[t] = v;
    __syncthreads();
    for (int off = 1; off < SC_T; off <<= 1) {
        const int u = (t >= off) ? sbuf[t - off] : 0;
        __syncthreads();
        sbuf[t] += u;
        __syncthreads();
    }
    if (i < NNODES) rowstart[i] = sbuf[t] - v;   // block-local exclusive
    if (t == SC_T - 1) partials[blockIdx.x] = sbuf[t];
}

__global__ void k_scan2(int* __restrict__ partials) {
    __shared__ int sbuf[128];
    const int t = threadIdx.x;
    const int v = (t < SC_B) ? partials[t] : 0;
    sbuf[t] = v;
    __syncthreads();
    for (int off = 1; off < 128; off <<= 1) {
        const int u = (t >= off) ? sbuf[t - off] : 0;
        __syncthreads();
        sbuf[t] += u;
        __syncthreads();
    }
    if (t < SC_B) partials[t] = sbuf[t] - v;     // exclusive block offsets
}

__global__ void k_scan3(int* __restrict__ rowstart,
                        const int* __restrict__ partials) {
    const int i = blockIdx.x * SC_T + threadIdx.x;
    if (i < NNODES) rowstart[i] += partials[blockIdx.x];
}

__global__ void k_fill(const int* __restrict__ ei,
                       const int* __restrict__ rowstart,
                       int* __restrict__ cursor,
                       int* __restrict__ sorted_src) {
    const int tid    = blockIdx.x * blockDim.x + threadIdx.x;
    const int stride = gridDim.x * blockDim.x;
    for (int e = tid; e < NEDGES; e += stride) {
        const int s = ei[e];
        const int d = ei[NEDGES + e];
        const int pos = atomicAdd(&cursor[d], 1);
        sorted_src[rowstart[d] + pos] = s;
    }
}

// ---------------------------------------------------------------------------
// K3: fused gather + MLP + BN-stats.
// Half-wave per node split as 4 edge-groups x 8 lanes; each group gathers one
// edge row as float4 (8x16B = one 128B line), 4 edges in flight. Butterfly
// (xor 8,16) merges groups; 32x32 MLP via unrolled shfl-extract.
// ---------------------------------------------------------------------------
__global__ void k_gather_mlp(const float* __restrict__ z,
                             const int* __restrict__ rowstart,
                             const int* __restrict__ deg,
                             const int* __restrict__ sorted_src,
                             const float* __restrict__ ba,
                             const float* __restrict__ wb,
                             const float* __restrict__ bb,
                             float* __restrict__ h,
                             float* __restrict__ stats) {
    __shared__ float sw[DIM * DIM];
    __shared__ float ssum[DIM], ssq[DIM];
    for (int i = threadIdx.x; i < DIM * DIM; i += blockDim.x) sw[i] = wb[i];
    if (threadIdx.x < DIM) { ssum[threadIdx.x] = 0.f; ssq[threadIdx.x] = 0.f; }
    __syncthreads();

    const int lane = threadIdx.x & 31;
    const int g    = lane >> 3;      // edge group 0..3
    const int f4   = lane & 7;       // float4 slot 0..7
    const float4 ba4 = reinterpret_cast<const float4*>(ba)[f4];
    const float bbk  = bb[lane];
    const int hw  = (blockIdx.x * blockDim.x + threadIdx.x) >> 5;
    const int nhw = (gridDim.x * blockDim.x) >> 5;

    float lsum = 0.f, lsq = 0.f;
    for (int i = hw; i < NNODES; i += nhw) {
        const int base = rowstart[i];
        const int cnt  = deg[i];
        float4 agg = make_float4(0.f, 0.f, 0.f, 0.f);
        for (int k0 = 0; k0 < cnt; k0 += 32) {
            int e = 0;
            if (k0 + lane < cnt) e = sorted_src[base + k0 + lane];
            const int m = min(32, cnt - k0);
            for (int j = 0; j < m; j += 4) {
                const int src = __shfl(e, j + g, 32);
                if (j + g < m) {
                    const float4 zv = *reinterpret_cast<const float4*>(&z[src * DIM + f4 * 4]);
                    agg.x += zv.x; agg.y += zv.y; agg.z += zv.z; agg.w += zv.w;
                }
            }
        }
#pragma unroll
        for (int mask = 8; mask <= 16; mask <<= 1) {
            agg.x += __shfl_xor(agg.x, mask, 32);
            agg.y += __shfl_xor(agg.y, mask, 32);
            agg.z += __shfl_xor(agg.z, mask, 32);
            agg.w += __shfl_xor(agg.w, mask, 32);
        }
        const float4 zi = *reinterpret_cast<const float4*>(&z[i * DIM + f4 * 4]);
        float t4[4];
        t4[0] = fmaxf(zi.x + agg.x + ba4.x, 0.f);
        t4[1] = fmaxf(zi.y + agg.y + ba4.y, 0.f);
        t4[2] = fmaxf(zi.z + agg.z + ba4.z, 0.f);
        t4[3] = fmaxf(zi.w + agg.w + ba4.w, 0.f);

        float acc = bbk;
#pragma unroll
        for (int j = 0; j < 32; ++j) {
            const float tj = __shfl(t4[j & 3], j >> 2, 32);
            acc += tj * sw[j * DIM + lane];
        }
        acc = fmaxf(acc, 0.f);
        h[i * DIM + lane] = acc;
        lsum += acc;
        lsq  += acc * acc;
    }
    atomicAdd(&ssum[lane], lsum);
    atomicAdd(&ssq[lane], lsq);
    __syncthreads();
    if (threadIdx.x < DIM) {
        atomicAdd(&stats[threadIdx.x],       ssum[threadIdx.x]);
        atomicAdd(&stats[DIM + threadIdx.x], ssq[threadIdx.x]);
    }
}

// ---------------------------------------------------------------------------
// K4: z = BN(h) @ wa, BN folded into the weights.
// ---------------------------------------------------------------------------
__global__ void k_projbn(const float* __restrict__ h,
                         const float* __restrict__ stats,
                         const float* __restrict__ g,
                         const float* __restrict__ be,
                         const float* __restrict__ wa,
                         float* __restrict__ z) {
    __shared__ float sw[DIM * DIM];
    __shared__ float sconst[DIM];
    __shared__ float ss[DIM], st[DIM];
    if (threadIdx.x < DIM) {
        float mu  = stats[threadIdx.x] * (1.f / NNODES);
        float var = stats[DIM + threadIdx.x] * (1.f / NNODES) - mu * mu;
        float sc  = g[threadIdx.x] * rsqrtf(var + BN_EPS);
        ss[threadIdx.x] = sc;
        st[threadIdx.x] = be[threadIdx.x] - mu * sc;
    }
    __syncthreads();
    for (int i = threadIdx.x; i < DIM * DIM; i += blockDim.x) {
        int j = i >> 5;
        sw[i] = ss[j] * wa[i];
    }
    __syncthreads();
    if (threadIdx.x < DIM) {
        float c = 0.f;
        for (int j = 0; j < DIM; ++j) c += st[j] * wa[j * DIM + threadIdx.x];
        sconst[threadIdx.x] = c;
    }
    __syncthreads();

    const int lane = threadIdx.x & 31;
    const int f4   = lane & 7;
    const int hw  = (blockIdx.x * blockDim.x + threadIdx.x) >> 5;
    const int nhw = (gridDim.x * blockDim.x) >> 5;
    for (int i = hw; i < NNODES; i += nhw) {
        const float4 hv = *reinterpret_cast<const float4*>(&h[i * DIM + f4 * 4]);
        float h4[4] = {hv.x, hv.y, hv.z, hv.w};
        float acc = sconst[lane];
#pragma unroll
        for (int j = 0; j < 32; ++j) {
            const float hj = __shfl(h4[j & 3], j >> 2, 32);
            acc += hj * sw[j * DIM + lane];
        }
        z[i * DIM + lane] = acc;
    }
}

// ---------------------------------------------------------------------------
// K5: head: out = relu(BN(h3) @ fw1 + fb1) @ fw2 + fb2   (N x 2)
// ---------------------------------------------------------------------------
__global__ void k_head(const float* __restrict__ h,
                       const float* __restrict__ stats,
                       const float* __restrict__ g,
                       const float* __restrict__ be,
                       const float* __restrict__ fw1,
                       const float* __restrict__ fb1,
                       const float* __restrict__ fw2,
                       const float* __restrict__ fb2,
                       float* __restrict__ out) {
    __shared__ float sw[DIM * DIM];
    __shared__ float sconst[DIM];
    __shared__ float ss[DIM], st[DIM];
    __shared__ float sw2[DIM * 2];
    if (threadIdx.x < DIM) {
        float mu  = stats[threadIdx.x] * (1.f / NNODES);
        float var = stats[DIM + threadIdx.x] * (1.f / NNODES) - mu * mu;
        float sc  = g[threadIdx.x] * rsqrtf(var + BN_EPS);
        ss[threadIdx.x] = sc;
        st[threadIdx.x] = be[threadIdx.x] - mu * sc;
    }
    __syncthreads();
    for (int i = threadIdx.x; i < DIM * DIM; i += blockDim.x) {
        int j = i >> 5;
        sw[i] = ss[j] * fw1[i];
    }
    if (threadIdx.x < DIM * 2) sw2[threadIdx.x] = fw2[threadIdx.x];
    __syncthreads();
    if (threadIdx.x < DIM) {
        float c = fb1[threadIdx.x];
        for (int j = 0; j < DIM; ++j) c += st[j] * fw1[j * DIM + threadIdx.x];
        sconst[threadIdx.x] = c;
    }
    __syncthreads();

    const float fb2_0 = fb2[0];
    const float fb2_1 = fb2[1];
    const int lane = threadIdx.x & 31;
    const int f4   = lane & 7;
    const int hw  = (blockIdx.x * blockDim.x + threadIdx.x) >> 5;
    const int nhw = (gridDim.x * blockDim.x) >> 5;
    for (int i = hw; i < NNODES; i += nhw) {
        const float4 hv = *reinterpret_cast<const float4*>(&h[i * DIM + f4 * 4]);
        float h4[4] = {hv.x, hv.y, hv.z, hv.w};
        float acc = sconst[lane];
#pragma unroll
        for (int j = 0; j < 32; ++j) {
            const float hj = __shfl(h4[j & 3], j >> 2, 32);
            acc += hj * sw[j * DIM + lane];
        }
        float u = fmaxf(acc, 0.f);
        float p0 = u * sw2[lane * 2 + 0];
        float p1 = u * sw2[lane * 2 + 1];
#pragma unroll
        for (int off = 16; off >= 1; off >>= 1) {
            p0 += __shfl_xor(p0, off, 32);
            p1 += __shfl_xor(p1, off, 32);
        }
        if (lane == 0) {
            out[i * 2 + 0] = p0 + fb2_0;
            out[i * 2 + 1] = p1 + fb2_1;
        }
    }
}

extern "C" void kernel_launch(void* const* d_in, const int* in_sizes, int n_in,
                              void* d_out, int out_size, void* d_ws, size_t ws_size,
                              hipStream_t stream) {
    const float* x   = (const float*)d_in[0];
    const int*   ei  = (const int*)d_in[1];
    const float* w1a = (const float*)d_in[4];
    const float* b1a = (const float*)d_in[5];
    const float* w1b = (const float*)d_in[6];
    const float* b1b = (const float*)d_in[7];
    const float* g1  = (const float*)d_in[8];
    const float* be1 = (const float*)d_in[9];
    const float* w2a = (const float*)d_in[10];
    const float* b2a = (const float*)d_in[11];
    const float* w2b = (const float*)d_in[12];
    const float* b2b = (const float*)d_in[13];
    const float* g2  = (const float*)d_in[14];
    const float* be2 = (const float*)d_in[15];
    const float* w3a = (const float*)d_in[16];
    const float* b3a = (const float*)d_in[17];
    const float* w3b = (const float*)d_in[18];
    const float* b3b = (const float*)d_in[19];
    const float* g3  = (const float*)d_in[20];
    const float* be3 = (const float*)d_in[21];
    const float* fw1 = (const float*)d_in[22];
    const float* fb1 = (const float*)d_in[23];
    const float* fw2 = (const float*)d_in[24];
    const float* fb2 = (const float*)d_in[25];
    float* out = (float*)d_out;

    float* ws = (float*)d_ws;
    const size_t nf = (size_t)NNODES * DIM;
    float* z     = ws;
    float* h     = ws + nf;
    float* stats = ws + 2 * nf;           // 3 layers x 64 floats
    int* deg        = (int*)(ws + 2 * nf + 192);
    int* rowstart   = deg + NNODES;
    int* cursor     = rowstart + NNODES;
    int* sorted_src = cursor + NNODES;    // NEDGES ints
    int* partials   = sorted_src + NEDGES; // 128 ints

    const int NB_NODE = 1024, NB_EDGE = 2048, TB = 256;

    hipMemsetAsync(stats, 0, 3 * 64 * sizeof(float), stream);
    hipMemsetAsync(deg, 0, NNODES * sizeof(int), stream);
    hipMemsetAsync(cursor, 0, NNODES * sizeof(int), stream);

    // CSR build (once; reused by all 3 layers)
    k_hist<<<NB_EDGE, TB, 0, stream>>>(ei, deg);
    k_scan1<<<SC_B, SC_T, 0, stream>>>(deg, rowstart, partials);
    k_scan2<<<1, 128, 0, stream>>>(partials);
    k_scan3<<<SC_B, SC_T, 0, stream>>>(rowstart, partials);
    k_fill<<<NB_EDGE, TB, 0, stream>>>(ei, rowstart, cursor, sorted_src);

    // ---- layer 1 ----
    k_proj1<<<NB_NODE, TB, 0, stream>>>(x, w1a, z);
    k_gather_mlp<<<NB_NODE, TB, 0, stream>>>(z, rowstart, deg, sorted_src,
                                             b1a, w1b, b1b, h, stats + 0);
    // ---- layer 2 ----
    k_projbn<<<NB_NODE, TB, 0, stream>>>(h, stats + 0, g1, be1, w2a, z);
    k_gather_mlp<<<NB_NODE, TB, 0, stream>>>(z, rowstart, deg, sorted_src,
                                             b2a, w2b, b2b, h, stats + 64);
    // ---- layer 3 ----
    k_projbn<<<NB_NODE, TB, 0, stream>>>(h, stats + 64, g2, be2, w3a, z);
    k_gather_mlp<<<NB_NODE, TB, 0, stream>>>(z, rowstart, deg, sorted_src,
                                             b3a, w3b, b3b, h, stats + 128);
    // ---- head ----
    k_head<<<NB_NODE, TB, 0, stream>>>(h, stats + 128, g3, be3,
                                       fw1, fb1, fw2, fb2, out);
}

// Round 4
// 509.243 us; speedup vs baseline: 4.4552x; 1.2095x over previous
//
#include <hip/hip_runtime.h>

#define NNODES 100000
#define NEDGES 1600000
#define FIN 128
#define DIM 32
#define BN_EPS 1e-5f
#define SC_T 1024
#define SC_B ((NNODES + SC_T - 1) / SC_T)   // 98 blocks
#define NB_TPN ((NNODES + 255) / 256)       // thread-per-node grid

// ---------------------------------------------------------------------------
// K1: z = x @ w1a  (N x 128)@(128 x 32). Thread-per-node: acc[32] in VGPRs,
// x row read in 128B chunks (8 dwordx4, line fully consumed), w via wave-
// uniform scalar loads (s_load + v_fma w/ SGPR operand) -> no LDS in loop.
// ---------------------------------------------------------------------------
__global__ void __launch_bounds__(256) k_proj1(const float* __restrict__ x,
                                               const float* __restrict__ w,
                                               float* __restrict__ z) {
    const int i = blockIdx.x * 256 + threadIdx.x;
    if (i >= NNODES) return;
    const float4* xp = reinterpret_cast<const float4*>(x + (size_t)i * FIN);
    float acc[DIM];
#pragma unroll
    for (int c = 0; c < DIM; ++c) acc[c] = 0.f;

    for (int k0 = 0; k0 < FIN; k0 += 32) {   // 4 chunks of 32 k
        float a[32];
        float4 r[8];
#pragma unroll
        for (int q = 0; q < 8; ++q) r[q] = xp[k0 / 4 + q];
#pragma unroll
        for (int q = 0; q < 8; ++q) {
            a[q * 4 + 0] = r[q].x; a[q * 4 + 1] = r[q].y;
            a[q * 4 + 2] = r[q].z; a[q * 4 + 3] = r[q].w;
        }
#pragma unroll
        for (int kk = 0; kk < 32; ++kk) {
            const float tk = a[kk];
#pragma unroll
            for (int c = 0; c < DIM; ++c)
                acc[c] += tk * w[(k0 + kk) * DIM + c];
        }
    }
    float4* zp = reinterpret_cast<float4*>(z + (size_t)i * DIM);
#pragma unroll
    for (int q = 0; q < 8; ++q)
        zp[q] = make_float4(acc[q * 4], acc[q * 4 + 1], acc[q * 4 + 2], acc[q * 4 + 3]);
}

// ---------------------------------------------------------------------------
// CSR build (graph identical across layers; built once per call).
// ---------------------------------------------------------------------------
__global__ void k_hist(const int* __restrict__ ei, int* __restrict__ deg) {
    const int tid    = blockIdx.x * blockDim.x + threadIdx.x;
    const int stride = gridDim.x * blockDim.x;
    for (int e = tid; e < NEDGES; e += stride)
        atomicAdd(&deg[ei[NEDGES + e]], 1);
}

__global__ void k_scan1(const int* __restrict__ deg,
                        int* __restrict__ rowstart,
                        int* __restrict__ partials) {
    __shared__ int sbuf[SC_T];
    const int t = threadIdx.x;
    const int i = blockIdx.x * SC_T + t;
    const int v = (i < NNODES) ? deg[i] : 0;
    sbuf[t] = v;
    __syncthreads();
    for (int off = 1; off < SC_T; off <<= 1) {
        const int u = (t >= off) ? sbuf[t - off] : 0;
        __syncthreads();
        sbuf[t] += u;
        __syncthreads();
    }
    if (i < NNODES) rowstart[i] = sbuf[t] - v;
    if (t == SC_T - 1) partials[blockIdx.x] = sbuf[t];
}

__global__ void k_scan2(int* __restrict__ partials) {
    __shared__ int sbuf[128];
    const int t = threadIdx.x;
    const int v = (t < SC_B) ? partials[t] : 0;
    sbuf[t] = v;
    __syncthreads();
    for (int off = 1; off < 128; off <<= 1) {
        const int u = (t >= off) ? sbuf[t - off] : 0;
        __syncthreads();
        sbuf[t] += u;
        __syncthreads();
    }
    if (t < SC_B) partials[t] = sbuf[t] - v;
}

__global__ void k_scan3(int* __restrict__ rowstart,
                        const int* __restrict__ partials) {
    const int i = blockIdx.x * SC_T + threadIdx.x;
    if (i < NNODES) rowstart[i] += partials[blockIdx.x];
}

__global__ void k_fill(const int* __restrict__ ei,
                       const int* __restrict__ rowstart,
                       int* __restrict__ cursor,
                       int* __restrict__ sorted_src) {
    const int tid    = blockIdx.x * blockDim.x + threadIdx.x;
    const int stride = gridDim.x * blockDim.x;
    for (int e = tid; e < NEDGES; e += stride) {
        const int s = ei[e];
        const int d = ei[NEDGES + e];
        const int pos = atomicAdd(&cursor[d], 1);
        sorted_src[rowstart[d] + pos] = s;
    }
}

// ---------------------------------------------------------------------------
// K3a: gather: t_i = relu(z_i + sum_{j in row} z_j + ba), written to tbuf.
// Half-wave per node; 4 edge-groups x 8 lanes, float4 row pieces; butterfly.
// ---------------------------------------------------------------------------
__global__ void k_gather_t(const float* __restrict__ z,
                           const int* __restrict__ rowstart,
                           const int* __restrict__ deg,
                           const int* __restrict__ sorted_src,
                           const float* __restrict__ ba,
                           float* __restrict__ tbuf) {
    const int lane = threadIdx.x & 31;
    const int g    = lane >> 3;
    const int f4   = lane & 7;
    const float4 ba4 = reinterpret_cast<const float4*>(ba)[f4];
    const int hw  = (blockIdx.x * blockDim.x + threadIdx.x) >> 5;
    const int nhw = (gridDim.x * blockDim.x) >> 5;

    for (int i = hw; i < NNODES; i += nhw) {
        const int base = rowstart[i];
        const int cnt  = deg[i];
        float4 agg = make_float4(0.f, 0.f, 0.f, 0.f);
        for (int k0 = 0; k0 < cnt; k0 += 32) {
            int e = 0;
            if (k0 + lane < cnt) e = sorted_src[base + k0 + lane];
            const int m = min(32, cnt - k0);
            for (int j = 0; j < m; j += 4) {
                const int src = __shfl(e, j + g, 32);
                if (j + g < m) {
                    const float4 zv = *reinterpret_cast<const float4*>(&z[src * DIM + f4 * 4]);
                    agg.x += zv.x; agg.y += zv.y; agg.z += zv.z; agg.w += zv.w;
                }
            }
        }
#pragma unroll
        for (int mask = 8; mask <= 16; mask <<= 1) {
            agg.x += __shfl_xor(agg.x, mask, 32);
            agg.y += __shfl_xor(agg.y, mask, 32);
            agg.z += __shfl_xor(agg.z, mask, 32);
            agg.w += __shfl_xor(agg.w, mask, 32);
        }
        if (g == 0) {
            const float4 zi = *reinterpret_cast<const float4*>(&z[i * DIM + f4 * 4]);
            float4 t;
            t.x = fmaxf(zi.x + agg.x + ba4.x, 0.f);
            t.y = fmaxf(zi.y + agg.y + ba4.y, 0.f);
            t.z = fmaxf(zi.z + agg.z + ba4.z, 0.f);
            t.w = fmaxf(zi.w + agg.w + ba4.w, 0.f);
            *reinterpret_cast<float4*>(&tbuf[i * DIM + f4 * 4]) = t;
        }
    }
}

// ---------------------------------------------------------------------------
// K3b: h = relu(t @ wb + bb), in place (reads row, writes same row).
// Thread-per-node, scalar-register weights. BN stats via 64-lane butterfly.
// ---------------------------------------------------------------------------
__global__ void __launch_bounds__(256) k_mlp2(float* __restrict__ hbuf,
                                              const float* __restrict__ wb,
                                              const float* __restrict__ bb,
                                              float* __restrict__ stats) {
    __shared__ float ssum[DIM], ssq[DIM];
    if (threadIdx.x < DIM) { ssum[threadIdx.x] = 0.f; ssq[threadIdx.x] = 0.f; }
    __syncthreads();

    const int i = blockIdx.x * 256 + threadIdx.x;
    const bool valid = i < NNODES;

    float a[DIM];
    if (valid) {
        const float4* tp = reinterpret_cast<const float4*>(hbuf + (size_t)i * DIM);
        float4 r[8];
#pragma unroll
        for (int q = 0; q < 8; ++q) r[q] = tp[q];
#pragma unroll
        for (int q = 0; q < 8; ++q) {
            a[q * 4 + 0] = r[q].x; a[q * 4 + 1] = r[q].y;
            a[q * 4 + 2] = r[q].z; a[q * 4 + 3] = r[q].w;
        }
    } else {
#pragma unroll
        for (int k = 0; k < DIM; ++k) a[k] = 0.f;
    }

    float acc[DIM];
#pragma unroll
    for (int c = 0; c < DIM; ++c) acc[c] = bb[c];
#pragma unroll
    for (int k = 0; k < DIM; ++k) {
        const float tk = a[k];
#pragma unroll
        for (int c = 0; c < DIM; ++c)
            acc[c] += tk * wb[k * DIM + c];
    }
#pragma unroll
    for (int c = 0; c < DIM; ++c) acc[c] = valid ? fmaxf(acc[c], 0.f) : 0.f;

    if (valid) {
        float4* hp = reinterpret_cast<float4*>(hbuf + (size_t)i * DIM);
#pragma unroll
        for (int q = 0; q < 8; ++q)
            hp[q] = make_float4(acc[q * 4], acc[q * 4 + 1], acc[q * 4 + 2], acc[q * 4 + 3]);
    }

    // BN stats: butterfly-reduce each feature across the 64-lane wave.
    const int lane = threadIdx.x & 63;
    float lsum = 0.f, lsq = 0.f;
#pragma unroll
    for (int c = 0; c < DIM; ++c) {
        float v = acc[c];
        float w2 = acc[c] * acc[c];
#pragma unroll
        for (int off = 1; off < 64; off <<= 1) {
            v  += __shfl_xor(v, off);
            w2 += __shfl_xor(w2, off);
        }
        if (lane == c) { lsum = v; lsq = w2; }
    }
    if (lane < DIM) {
        atomicAdd(&ssum[lane], lsum);
        atomicAdd(&ssq[lane], lsq);
    }
    __syncthreads();
    if (threadIdx.x < DIM) {
        atomicAdd(&stats[threadIdx.x],       ssum[threadIdx.x]);
        atomicAdd(&stats[DIM + threadIdx.x], ssq[threadIdx.x]);
    }
}

// ---------------------------------------------------------------------------
// K4: z = BN(h) @ wa. Thread-per-node; BN scales recomputed per-k from
// wave-uniform scalar loads (cheap VALU, no fold kernel needed).
// ---------------------------------------------------------------------------
__global__ void __launch_bounds__(256) k_projbn(const float* __restrict__ h,
                                                const float* __restrict__ stats,
                                                const float* __restrict__ g,
                                                const float* __restrict__ be,
                                                const float* __restrict__ wa,
                                                float* __restrict__ z) {
    const int i = blockIdx.x * 256 + threadIdx.x;
    if (i >= NNODES) return;
    const float4* hp = reinterpret_cast<const float4*>(h + (size_t)i * DIM);
    float a[DIM];
    float4 r[8];
#pragma unroll
    for (int q = 0; q < 8; ++q) r[q] = hp[q];
#pragma unroll
    for (int q = 0; q < 8; ++q) {
        a[q * 4 + 0] = r[q].x; a[q * 4 + 1] = r[q].y;
        a[q * 4 + 2] = r[q].z; a[q * 4 + 3] = r[q].w;
    }
    float acc[DIM];
#pragma unroll
    for (int c = 0; c < DIM; ++c) acc[c] = 0.f;
#pragma unroll
    for (int k = 0; k < DIM; ++k) {
        const float mu  = stats[k] * (1.f / NNODES);
        const float var = stats[DIM + k] * (1.f / NNODES) - mu * mu;
        const float ss  = g[k] * rsqrtf(var + BN_EPS);
        const float st  = be[k] - mu * ss;
        const float tk  = a[k] * ss + st;
#pragma unroll
        for (int c = 0; c < DIM; ++c)
            acc[c] += tk * wa[k * DIM + c];
    }
    float4* zp = reinterpret_cast<float4*>(z + (size_t)i * DIM);
#pragma unroll
    for (int q = 0; q < 8; ++q)
        zp[q] = make_float4(acc[q * 4], acc[q * 4 + 1], acc[q * 4 + 2], acc[q * 4 + 3]);
}

// ---------------------------------------------------------------------------
// K5: head: out = relu(BN(h3) @ fw1 + fb1) @ fw2 + fb2   (N x 2)
// ---------------------------------------------------------------------------
__global__ void __launch_bounds__(256) k_head(const float* __restrict__ h,
                                              const float* __restrict__ stats,
                                              const float* __restrict__ g,
                                              const float* __restrict__ be,
                                              const float* __restrict__ fw1,
                                              const float* __restrict__ fb1,
                                              const float* __restrict__ fw2,
                                              const float* __restrict__ fb2,
                                              float* __restrict__ out) {
    const int i = blockIdx.x * 256 + threadIdx.x;
    if (i >= NNODES) return;
    const float4* hp = reinterpret_cast<const float4*>(h + (size_t)i * DIM);
    float a[DIM];
    float4 r[8];
#pragma unroll
    for (int q = 0; q < 8; ++q) r[q] = hp[q];
#pragma unroll
    for (int q = 0; q < 8; ++q) {
        a[q * 4 + 0] = r[q].x; a[q * 4 + 1] = r[q].y;
        a[q * 4 + 2] = r[q].z; a[q * 4 + 3] = r[q].w;
    }
    float acc[DIM];
#pragma unroll
    for (int c = 0; c < DIM; ++c) acc[c] = fb1[c];
#pragma unroll
    for (int k = 0; k < DIM; ++k) {
        const float mu  = stats[k] * (1.f / NNODES);
        const float var = stats[DIM + k] * (1.f / NNODES) - mu * mu;
        const float ss  = g[k] * rsqrtf(var + BN_EPS);
        const float st  = be[k] - mu * ss;
        const float tk  = a[k] * ss + st;
#pragma unroll
        for (int c = 0; c < DIM; ++c)
            acc[c] += tk * fw1[k * DIM + c];
    }
    float o0 = fb2[0], o1 = fb2[1];
#pragma unroll
    for (int c = 0; c < DIM; ++c) {
        const float u = fmaxf(acc[c], 0.f);
        o0 += u * fw2[c * 2 + 0];
        o1 += u * fw2[c * 2 + 1];
    }
    *reinterpret_cast<float2*>(&out[i * 2]) = make_float2(o0, o1);
}

extern "C" void kernel_launch(void* const* d_in, const int* in_sizes, int n_in,
                              void* d_out, int out_size, void* d_ws, size_t ws_size,
                              hipStream_t stream) {
    const float* x   = (const float*)d_in[0];
    const int*   ei  = (const int*)d_in[1];
    const float* w1a = (const float*)d_in[4];
    const float* b1a = (const float*)d_in[5];
    const float* w1b = (const float*)d_in[6];
    const float* b1b = (const float*)d_in[7];
    const float* g1  = (const float*)d_in[8];
    const float* be1 = (const float*)d_in[9];
    const float* w2a = (const float*)d_in[10];
    const float* b2a = (const float*)d_in[11];
    const float* w2b = (const float*)d_in[12];
    const float* b2b = (const float*)d_in[13];
    const float* g2  = (const float*)d_in[14];
    const float* be2 = (const float*)d_in[15];
    const float* w3a = (const float*)d_in[16];
    const float* b3a = (const float*)d_in[17];
    const float* w3b = (const float*)d_in[18];
    const float* b3b = (const float*)d_in[19];
    const float* g3  = (const float*)d_in[20];
    const float* be3 = (const float*)d_in[21];
    const float* fw1 = (const float*)d_in[22];
    const float* fb1 = (const float*)d_in[23];
    const float* fw2 = (const float*)d_in[24];
    const float* fb2 = (const float*)d_in[25];
    float* out = (float*)d_out;

    float* ws = (float*)d_ws;
    const size_t nf = (size_t)NNODES * DIM;
    float* z     = ws;
    float* h     = ws + nf;               // holds t, then h in place
    float* stats = ws + 2 * nf;           // 3 layers x 64 floats
    int* deg        = (int*)(ws + 2 * nf + 192);
    int* rowstart   = deg + NNODES;
    int* cursor     = rowstart + NNODES;
    int* sorted_src = cursor + NNODES;    // NEDGES ints
    int* partials   = sorted_src + NEDGES; // 128 ints

    const int NB_EDGE = 2048, TB = 256, NB_G = 1024;

    hipMemsetAsync(stats, 0, 3 * 64 * sizeof(float), stream);
    hipMemsetAsync(deg, 0, NNODES * sizeof(int), stream);
    hipMemsetAsync(cursor, 0, NNODES * sizeof(int), stream);

    // CSR build (once; reused by all 3 layers)
    k_hist<<<NB_EDGE, TB, 0, stream>>>(ei, deg);
    k_scan1<<<SC_B, SC_T, 0, stream>>>(deg, rowstart, partials);
    k_scan2<<<1, 128, 0, stream>>>(partials);
    k_scan3<<<SC_B, SC_T, 0, stream>>>(rowstart, partials);
    k_fill<<<NB_EDGE, TB, 0, stream>>>(ei, rowstart, cursor, sorted_src);

    // ---- layer 1 ----
    k_proj1<<<NB_TPN, TB, 0, stream>>>(x, w1a, z);
    k_gather_t<<<NB_G, TB, 0, stream>>>(z, rowstart, deg, sorted_src, b1a, h);
    k_mlp2<<<NB_TPN, TB, 0, stream>>>(h, w1b, b1b, stats + 0);
    // ---- layer 2 ----
    k_projbn<<<NB_TPN, TB, 0, stream>>>(h, stats + 0, g1, be1, w2a, z);
    k_gather_t<<<NB_G, TB, 0, stream>>>(z, rowstart, deg, sorted_src, b2a, h);
    k_mlp2<<<NB_TPN, TB, 0, stream>>>(h, w2b, b2b, stats + 64);
    // ---- layer 3 ----
    k_projbn<<<NB_TPN, TB, 0, stream>>>(h, stats + 64, g2, be2, w3a, z);
    k_gather_t<<<NB_G, TB, 0, stream>>>(z, rowstart, deg, sorted_src, b3a, h);
    k_mlp2<<<NB_TPN, TB, 0, stream>>>(h, w3b, b3b, stats + 128);
    // ---- head ----
    k_head<<<NB_TPN, TB, 0, stream>>>(h, stats + 128, g3, be3,
                                      fw1, fb1, fw2, fb2, out);
}

// Round 5
// 350.335 us; speedup vs baseline: 6.4760x; 1.4536x over previous
//
#include <hip/hip_runtime.h>

#define NNODES 100000
#define NEDGES 1600000
#define FIN 128
#define DIM 32
#define BN_EPS 1e-5f
#define NB_TPN ((NNODES + 255) / 256)       // thread-per-node grid
#define NBUK ((NNODES + 255) >> 8)          // 391 buckets of 256 nodes
#define CH 8192                             // edges per scatter block

// ---------------------------------------------------------------------------
// K1: z = x @ w1a  (N x 128)@(128 x 32). Thread-per-node; weights via
// wave-uniform scalar loads -> no LDS in the inner loop.
// ---------------------------------------------------------------------------
__global__ void __launch_bounds__(256) k_proj1(const float* __restrict__ x,
                                               const float* __restrict__ w,
                                               float* __restrict__ z) {
    const int i = blockIdx.x * 256 + threadIdx.x;
    if (i >= NNODES) return;
    const float4* xp = reinterpret_cast<const float4*>(x + (size_t)i * FIN);
    float acc[DIM];
#pragma unroll
    for (int c = 0; c < DIM; ++c) acc[c] = 0.f;

    for (int k0 = 0; k0 < FIN; k0 += 32) {
        float a[32];
        float4 r[8];
#pragma unroll
        for (int q = 0; q < 8; ++q) r[q] = xp[k0 / 4 + q];
#pragma unroll
        for (int q = 0; q < 8; ++q) {
            a[q * 4 + 0] = r[q].x; a[q * 4 + 1] = r[q].y;
            a[q * 4 + 2] = r[q].z; a[q * 4 + 3] = r[q].w;
        }
#pragma unroll
        for (int kk = 0; kk < 32; ++kk) {
            const float tk = a[kk];
#pragma unroll
            for (int c = 0; c < DIM; ++c)
                acc[c] += tk * w[(k0 + kk) * DIM + c];
        }
    }
    float4* zp = reinterpret_cast<float4*>(z + (size_t)i * DIM);
#pragma unroll
    for (int q = 0; q < 8; ++q)
        zp[q] = make_float4(acc[q * 4], acc[q * 4 + 1], acc[q * 4 + 2], acc[q * 4 + 3]);
}

// ---------------------------------------------------------------------------
// Bucketed CSR build. Bucket b = nodes [b*256, b*256+256).
// F1: global bucket histogram (LDS-aggregated).
// ---------------------------------------------------------------------------
__global__ void k_bhist(const int* __restrict__ ei, int* __restrict__ bucketCnt) {
    __shared__ int cnt[NBUK];
    for (int i = threadIdx.x; i < NBUK; i += 256) cnt[i] = 0;
    __syncthreads();
    const int tid    = blockIdx.x * blockDim.x + threadIdx.x;
    const int stride = gridDim.x * blockDim.x;
    for (int e = tid; e < NEDGES; e += stride)
        atomicAdd(&cnt[ei[NEDGES + e] >> 8], 1);
    __syncthreads();
    for (int i = threadIdx.x; i < NBUK; i += 256)
        if (cnt[i]) atomicAdd(&bucketCnt[i], cnt[i]);
}

// F2: one-block scan of bucket counts -> bbase (exclusive) + gcur copy.
__global__ void k_bscan(const int* __restrict__ bucketCnt,
                        int* __restrict__ bbase, int* __restrict__ gcur) {
    __shared__ int sbuf[512];
    const int t = threadIdx.x;
    const int v = (t < NBUK) ? bucketCnt[t] : 0;
    sbuf[t] = v;
    __syncthreads();
    for (int off = 1; off < 512; off <<= 1) {
        const int u = (t >= off) ? sbuf[t - off] : 0;
        __syncthreads();
        sbuf[t] += u;
        __syncthreads();
    }
    if (t < NBUK) { const int ex = sbuf[t] - v; bbase[t] = ex; gcur[t] = ex; }
    if (t == 0) bbase[NBUK] = NEDGES;
}

// F3: chunk-local scatter into bucket-grouped (src,dst) pairs.
// Per block: LDS count over its CH edges, one global atomic per bucket to
// reserve a chunk, then grouped writes (contiguous runs per bucket).
__global__ void __launch_bounds__(256) k_bscatter(const int* __restrict__ ei,
                                                  int* __restrict__ gcur,
                                                  int2* __restrict__ bucketed) {
    __shared__ int cnt[NBUK];
    __shared__ int base[NBUK];
    const int start = blockIdx.x * CH;
    const int end   = min(start + CH, NEDGES);
    for (int i = threadIdx.x; i < NBUK; i += 256) cnt[i] = 0;
    __syncthreads();
    for (int e = start + threadIdx.x; e < end; e += 256)
        atomicAdd(&cnt[ei[NEDGES + e] >> 8], 1);
    __syncthreads();
    for (int i = threadIdx.x; i < NBUK; i += 256) {
        const int c = cnt[i];
        base[i] = c ? atomicAdd(&gcur[i], c) : 0;
        cnt[i] = 0;
    }
    __syncthreads();
    for (int e = start + threadIdx.x; e < end; e += 256) {
        const int s = ei[e];
        const int d = ei[NEDGES + e];
        const int b = d >> 8;
        const int p = atomicAdd(&cnt[b], 1);
        bucketed[base[b] + p] = make_int2(s, d);
    }
}

// F4: one block per bucket. Local degree count -> local scan gives
// rowstart+deg (no separate hist/scan kernels); LDS-cursor fill. All
// sorted_src writes land in a ~16KB window -> full-line write-backs.
__global__ void __launch_bounds__(256) k_bfill(const int2* __restrict__ bucketed,
                                               const int* __restrict__ bbase,
                                               int* __restrict__ rowstart,
                                               int* __restrict__ deg,
                                               int* __restrict__ sorted_src) {
    __shared__ int dcnt[256], dsc[256], cur[256];
    const int b  = blockIdx.x;
    const int lo = bbase[b];
    const int hi = bbase[b + 1];
    const int n0 = b << 8;
    const int t  = threadIdx.x;
    dcnt[t] = 0;
    __syncthreads();
    for (int p = lo + t; p < hi; p += 256)
        atomicAdd(&dcnt[bucketed[p].y - n0], 1);
    __syncthreads();
    const int myc = dcnt[t];
    dsc[t] = myc;
    __syncthreads();
    for (int off = 1; off < 256; off <<= 1) {
        const int u = (t >= off) ? dsc[t - off] : 0;
        __syncthreads();
        dsc[t] += u;
        __syncthreads();
    }
    const int ex = dsc[t] - myc;          // local exclusive
    const int node = n0 + t;
    if (node < NNODES) { rowstart[node] = lo + ex; deg[node] = myc; }
    dcnt[t] = ex;                          // reuse as local base
    cur[t] = 0;
    __syncthreads();
    for (int p = lo + t; p < hi; p += 256) {
        const int2 sd = bucketed[p];
        const int dl = sd.y - n0;
        const int pos = atomicAdd(&cur[dl], 1);
        sorted_src[lo + dcnt[dl] + pos] = sd.x;
    }
}

// ---------------------------------------------------------------------------
// K3a: gather: t_i = relu(z_i + sum_{j in row} z_j + ba) -> tbuf.
// Half-wave per node; 4 groups x 8 lanes, 2 edges per group in flight
// (dual float4 accumulators); butterfly merge.
// ---------------------------------------------------------------------------
__global__ void k_gather_t(const float* __restrict__ z,
                           const int* __restrict__ rowstart,
                           const int* __restrict__ deg,
                           const int* __restrict__ sorted_src,
                           const float* __restrict__ ba,
                           float* __restrict__ tbuf) {
    const int lane = threadIdx.x & 31;
    const int g    = lane >> 3;
    const int f4   = lane & 7;
    const float4 ba4 = reinterpret_cast<const float4*>(ba)[f4];
    const int hw  = (blockIdx.x * blockDim.x + threadIdx.x) >> 5;
    const int nhw = (gridDim.x * blockDim.x) >> 5;

    for (int i = hw; i < NNODES; i += nhw) {
        const int base = rowstart[i];
        const int cnt  = deg[i];
        float4 agg0 = make_float4(0.f, 0.f, 0.f, 0.f);
        float4 agg1 = make_float4(0.f, 0.f, 0.f, 0.f);
        for (int k0 = 0; k0 < cnt; k0 += 32) {
            int e = 0;
            if (k0 + lane < cnt) e = sorted_src[base + k0 + lane];
            const int m = min(32, cnt - k0);
            for (int j = 0; j < m; j += 8) {
                const int s0 = __shfl(e, j + g, 32);
                const int s1 = __shfl(e, j + 4 + g, 32);
                if (j + g < m) {
                    const float4 zv = *reinterpret_cast<const float4*>(&z[s0 * DIM + f4 * 4]);
                    agg0.x += zv.x; agg0.y += zv.y; agg0.z += zv.z; agg0.w += zv.w;
                }
                if (j + 4 + g < m) {
                    const float4 zv = *reinterpret_cast<const float4*>(&z[s1 * DIM + f4 * 4]);
                    agg1.x += zv.x; agg1.y += zv.y; agg1.z += zv.z; agg1.w += zv.w;
                }
            }
        }
        agg0.x += agg1.x; agg0.y += agg1.y; agg0.z += agg1.z; agg0.w += agg1.w;
#pragma unroll
        for (int mask = 8; mask <= 16; mask <<= 1) {
            agg0.x += __shfl_xor(agg0.x, mask, 32);
            agg0.y += __shfl_xor(agg0.y, mask, 32);
            agg0.z += __shfl_xor(agg0.z, mask, 32);
            agg0.w += __shfl_xor(agg0.w, mask, 32);
        }
        if (g == 0) {
            const float4 zi = *reinterpret_cast<const float4*>(&z[i * DIM + f4 * 4]);
            float4 t;
            t.x = fmaxf(zi.x + agg0.x + ba4.x, 0.f);
            t.y = fmaxf(zi.y + agg0.y + ba4.y, 0.f);
            t.z = fmaxf(zi.z + agg0.z + ba4.z, 0.f);
            t.w = fmaxf(zi.w + agg0.w + ba4.w, 0.f);
            *reinterpret_cast<float4*>(&tbuf[i * DIM + f4 * 4]) = t;
        }
    }
}

// ---------------------------------------------------------------------------
// K3b: h = relu(t @ wb + bb) in place. BN stats via 64-lane butterfly.
// ---------------------------------------------------------------------------
__global__ void __launch_bounds__(256) k_mlp2(float* __restrict__ hbuf,
                                              const float* __restrict__ wb,
                                              const float* __restrict__ bb,
                                              float* __restrict__ stats) {
    __shared__ float ssum[DIM], ssq[DIM];
    if (threadIdx.x < DIM) { ssum[threadIdx.x] = 0.f; ssq[threadIdx.x] = 0.f; }
    __syncthreads();

    const int i = blockIdx.x * 256 + threadIdx.x;
    const bool valid = i < NNODES;

    float a[DIM];
    if (valid) {
        const float4* tp = reinterpret_cast<const float4*>(hbuf + (size_t)i * DIM);
        float4 r[8];
#pragma unroll
        for (int q = 0; q < 8; ++q) r[q] = tp[q];
#pragma unroll
        for (int q = 0; q < 8; ++q) {
            a[q * 4 + 0] = r[q].x; a[q * 4 + 1] = r[q].y;
            a[q * 4 + 2] = r[q].z; a[q * 4 + 3] = r[q].w;
        }
    } else {
#pragma unroll
        for (int k = 0; k < DIM; ++k) a[k] = 0.f;
    }

    float acc[DIM];
#pragma unroll
    for (int c = 0; c < DIM; ++c) acc[c] = bb[c];
#pragma unroll
    for (int k = 0; k < DIM; ++k) {
        const float tk = a[k];
#pragma unroll
        for (int c = 0; c < DIM; ++c)
            acc[c] += tk * wb[k * DIM + c];
    }
#pragma unroll
    for (int c = 0; c < DIM; ++c) acc[c] = valid ? fmaxf(acc[c], 0.f) : 0.f;

    if (valid) {
        float4* hp = reinterpret_cast<float4*>(hbuf + (size_t)i * DIM);
#pragma unroll
        for (int q = 0; q < 8; ++q)
            hp[q] = make_float4(acc[q * 4], acc[q * 4 + 1], acc[q * 4 + 2], acc[q * 4 + 3]);
    }

    const int lane = threadIdx.x & 63;
    float lsum = 0.f, lsq = 0.f;
#pragma unroll
    for (int c = 0; c < DIM; ++c) {
        float v  = acc[c];
        float w2 = acc[c] * acc[c];
#pragma unroll
        for (int off = 1; off < 64; off <<= 1) {
            v  += __shfl_xor(v, off);
            w2 += __shfl_xor(w2, off);
        }
        if (lane == c) { lsum = v; lsq = w2; }
    }
    if (lane < DIM) {
        atomicAdd(&ssum[lane], lsum);
        atomicAdd(&ssq[lane], lsq);
    }
    __syncthreads();
    if (threadIdx.x < DIM) {
        atomicAdd(&stats[threadIdx.x],       ssum[threadIdx.x]);
        atomicAdd(&stats[DIM + threadIdx.x], ssq[threadIdx.x]);
    }
}

// ---------------------------------------------------------------------------
// K4: z = BN(h) @ wa. Thread-per-node; BN folded per-k from scalar loads.
// ---------------------------------------------------------------------------
__global__ void __launch_bounds__(256) k_projbn(const float* __restrict__ h,
                                                const float* __restrict__ stats,
                                                const float* __restrict__ g,
                                                const float* __restrict__ be,
                                                const float* __restrict__ wa,
                                                float* __restrict__ z) {
    const int i = blockIdx.x * 256 + threadIdx.x;
    if (i >= NNODES) return;
    const float4* hp = reinterpret_cast<const float4*>(h + (size_t)i * DIM);
    float a[DIM];
    float4 r[8];
#pragma unroll
    for (int q = 0; q < 8; ++q) r[q] = hp[q];
#pragma unroll
    for (int q = 0; q < 8; ++q) {
        a[q * 4 + 0] = r[q].x; a[q * 4 + 1] = r[q].y;
        a[q * 4 + 2] = r[q].z; a[q * 4 + 3] = r[q].w;
    }
    float acc[DIM];
#pragma unroll
    for (int c = 0; c < DIM; ++c) acc[c] = 0.f;
#pragma unroll
    for (int k = 0; k < DIM; ++k) {
        const float mu  = stats[k] * (1.f / NNODES);
        const float var = stats[DIM + k] * (1.f / NNODES) - mu * mu;
        const float ss  = g[k] * rsqrtf(var + BN_EPS);
        const float st  = be[k] - mu * ss;
        const float tk  = a[k] * ss + st;
#pragma unroll
        for (int c = 0; c < DIM; ++c)
            acc[c] += tk * wa[k * DIM + c];
    }
    float4* zp = reinterpret_cast<float4*>(z + (size_t)i * DIM);
#pragma unroll
    for (int q = 0; q < 8; ++q)
        zp[q] = make_float4(acc[q * 4], acc[q * 4 + 1], acc[q * 4 + 2], acc[q * 4 + 3]);
}

// ---------------------------------------------------------------------------
// K5: head: out = relu(BN(h3) @ fw1 + fb1) @ fw2 + fb2   (N x 2)
// ---------------------------------------------------------------------------
__global__ void __launch_bounds__(256) k_head(const float* __restrict__ h,
                                              const float* __restrict__ stats,
                                              const float* __restrict__ g,
                                              const float* __restrict__ be,
                                              const float* __restrict__ fw1,
                                              const float* __restrict__ fb1,
                                              const float* __restrict__ fw2,
                                              const float* __restrict__ fb2,
                                              float* __restrict__ out) {
    const int i = blockIdx.x * 256 + threadIdx.x;
    if (i >= NNODES) return;
    const float4* hp = reinterpret_cast<const float4*>(h + (size_t)i * DIM);
    float a[DIM];
    float4 r[8];
#pragma unroll
    for (int q = 0; q < 8; ++q) r[q] = hp[q];
#pragma unroll
    for (int q = 0; q < 8; ++q) {
        a[q * 4 + 0] = r[q].x; a[q * 4 + 1] = r[q].y;
        a[q * 4 + 2] = r[q].z; a[q * 4 + 3] = r[q].w;
    }
    float acc[DIM];
#pragma unroll
    for (int c = 0; c < DIM; ++c) acc[c] = fb1[c];
#pragma unroll
    for (int k = 0; k < DIM; ++k) {
        const float mu  = stats[k] * (1.f / NNODES);
        const float var = stats[DIM + k] * (1.f / NNODES) - mu * mu;
        const float ss  = g[k] * rsqrtf(var + BN_EPS);
        const float st  = be[k] - mu * ss;
        const float tk  = a[k] * ss + st;
#pragma unroll
        for (int c = 0; c < DIM; ++c)
            acc[c] += tk * fw1[k * DIM + c];
    }
    float o0 = fb2[0], o1 = fb2[1];
#pragma unroll
    for (int c = 0; c < DIM; ++c) {
        const float u = fmaxf(acc[c], 0.f);
        o0 += u * fw2[c * 2 + 0];
        o1 += u * fw2[c * 2 + 1];
    }
    *reinterpret_cast<float2*>(&out[i * 2]) = make_float2(o0, o1);
}

extern "C" void kernel_launch(void* const* d_in, const int* in_sizes, int n_in,
                              void* d_out, int out_size, void* d_ws, size_t ws_size,
                              hipStream_t stream) {
    const float* x   = (const float*)d_in[0];
    const int*   ei  = (const int*)d_in[1];
    const float* w1a = (const float*)d_in[4];
    const float* b1a = (const float*)d_in[5];
    const float* w1b = (const float*)d_in[6];
    const float* b1b = (const float*)d_in[7];
    const float* g1  = (const float*)d_in[8];
    const float* be1 = (const float*)d_in[9];
    const float* w2a = (const float*)d_in[10];
    const float* b2a = (const float*)d_in[11];
    const float* w2b = (const float*)d_in[12];
    const float* b2b = (const float*)d_in[13];
    const float* g2  = (const float*)d_in[14];
    const float* be2 = (const float*)d_in[15];
    const float* w3a = (const float*)d_in[16];
    const float* b3a = (const float*)d_in[17];
    const float* w3b = (const float*)d_in[18];
    const float* b3b = (const float*)d_in[19];
    const float* g3  = (const float*)d_in[20];
    const float* be3 = (const float*)d_in[21];
    const float* fw1 = (const float*)d_in[22];
    const float* fb1 = (const float*)d_in[23];
    const float* fw2 = (const float*)d_in[24];
    const float* fb2 = (const float*)d_in[25];
    float* out = (float*)d_out;

    float* ws = (float*)d_ws;
    const size_t nf = (size_t)NNODES * DIM;
    float* z     = ws;
    float* h     = ws + nf;                       // aliases bucketed (int2[NEDGES])
    int2*  bucketed = (int2*)h;                   // NEDGES*8B == nf*4B exactly
    float* stats = ws + 2 * nf;                   // 3 layers x 64 floats
    int* rowstart   = (int*)(ws + 2 * nf + 192);
    int* deg        = rowstart + NNODES;
    int* sorted_src = deg + NNODES;               // NEDGES ints
    int* bucketCnt  = sorted_src + NEDGES;        // NBUK
    int* bbase      = bucketCnt + NBUK;           // NBUK+1
    int* gcur       = bbase + NBUK + 1;           // NBUK

    const int TB = 256, NB_G = 2048;

    hipMemsetAsync(stats, 0, 3 * 64 * sizeof(float), stream);
    hipMemsetAsync(bucketCnt, 0, NBUK * sizeof(int), stream);

    // Bucketed CSR build (once; reused by all 3 layers)
    k_bhist<<<512, TB, 0, stream>>>(ei, bucketCnt);
    k_bscan<<<1, 512, 0, stream>>>(bucketCnt, bbase, gcur);
    k_bscatter<<<(NEDGES + CH - 1) / CH, TB, 0, stream>>>(ei, gcur, bucketed);
    k_bfill<<<NBUK, TB, 0, stream>>>(bucketed, bbase, rowstart, deg, sorted_src);

    // ---- layer 1 ----
    k_proj1<<<NB_TPN, TB, 0, stream>>>(x, w1a, z);
    k_gather_t<<<NB_G, TB, 0, stream>>>(z, rowstart, deg, sorted_src, b1a, h);
    k_mlp2<<<NB_TPN, TB, 0, stream>>>(h, w1b, b1b, stats + 0);
    // ---- layer 2 ----
    k_projbn<<<NB_TPN, TB, 0, stream>>>(h, stats + 0, g1, be1, w2a, z);
    k_gather_t<<<NB_G, TB, 0, stream>>>(z, rowstart, deg, sorted_src, b2a, h);
    k_mlp2<<<NB_TPN, TB, 0, stream>>>(h, w2b, b2b, stats + 64);
    // ---- layer 3 ----
    k_projbn<<<NB_TPN, TB, 0, stream>>>(h, stats + 64, g2, be2, w3a, z);
    k_gather_t<<<NB_G, TB, 0, stream>>>(z, rowstart, deg, sorted_src, b3a, h);
    k_mlp2<<<NB_TPN, TB, 0, stream>>>(h, w3b, b3b, stats + 128);
    // ---- head ----
    k_head<<<NB_TPN, TB, 0, stream>>>(h, stats + 128, g3, be3,
                                      fw1, fb1, fw2, fb2, out);
}